// Round 1
// baseline (40.484 us; speedup 1.0000x reference)
//
#include <hip/hip_runtime.h>

#define NS 131072
#define D 16
#define R 32
#define O 10
#define EPSF 1e-8f

// Prologue: nw[r*D+d] = -1/(2*sigma^2). 512 elements into d_ws.
__global__ void anfis_prep(const float* __restrict__ sigmas, float* __restrict__ nw) {
    int i = blockIdx.x * blockDim.x + threadIdx.x;
    if (i < R * D) {
        float s = sigmas[i];
        nw[i] = -1.0f / (2.0f * s * s);
    }
}

__global__ __launch_bounds__(256) void anfis_main(
    const float* __restrict__ X,
    const float* __restrict__ centers,
    const float* __restrict__ nw,
    const float* __restrict__ coeffs,
    float* __restrict__ out)
{
    const int n = blockIdx.x * blockDim.x + threadIdx.x;

    // Load this sample's 16 features (4x float4, 64B/thread, wave covers 4KB contiguous).
    float x[D];
    const float4* xp = reinterpret_cast<const float4*>(X + (size_t)n * D);
    #pragma unroll
    for (int i = 0; i < 4; ++i) {
        float4 v = xp[i];
        x[4*i+0] = v.x; x[4*i+1] = v.y; x[4*i+2] = v.z; x[4*i+3] = v.w;
    }

    float acc[O];
    #pragma unroll
    for (int o = 0; o < O; ++o) acc[o] = 0.0f;
    float ssum = 0.0f;

    for (int r = 0; r < R; ++r) {
        // Membership: exp( sum_d (x-c)^2 * (-1/(2 sigma^2)) )
        const float* cr = centers + r * D;
        const float* wr = nw + r * D;
        float e = 0.0f;
        #pragma unroll
        for (int d = 0; d < D; ++d) {
            float df = x[d] - cr[d];
            e = fmaf(df * df, wr[d], e);
        }
        float s = __expf(e);
        ssum += s;

        // Consequent: wi_o = bias + sum_d x_d * C[r,d,o]; acc_o += s * wi_o
        const float* co = coeffs + (size_t)r * (D + 1) * O;
        float wi[O];
        #pragma unroll
        for (int o = 0; o < O; ++o) wi[o] = co[D * O + o];   // bias row (i = D)
        #pragma unroll
        for (int d = 0; d < D; ++d) {
            float xd = x[d];
            #pragma unroll
            for (int o = 0; o < O; ++o) wi[o] = fmaf(xd, co[d * O + o], wi[o]);
        }
        #pragma unroll
        for (int o = 0; o < O; ++o) acc[o] = fmaf(s, wi[o], acc[o]);
    }

    // Normalize (fold into softmax exponent) + softmax over O.
    const float inv = 1.0f / (ssum + EPSF);
    float m = acc[0];
    #pragma unroll
    for (int o = 1; o < O; ++o) m = fmaxf(m, acc[o]);
    float e_[O];
    float se = 0.0f;
    #pragma unroll
    for (int o = 0; o < O; ++o) {
        e_[o] = __expf((acc[o] - m) * inv);
        se += e_[o];
    }
    const float rs = 1.0f / se;

    float2* op = reinterpret_cast<float2*>(out + (size_t)n * O);
    #pragma unroll
    for (int i = 0; i < 5; ++i) {
        op[i] = make_float2(e_[2*i] * rs, e_[2*i+1] * rs);
    }
}

extern "C" void kernel_launch(void* const* d_in, const int* in_sizes, int n_in,
                              void* d_out, int out_size, void* d_ws, size_t ws_size,
                              hipStream_t stream) {
    const float* X       = (const float*)d_in[0];
    const float* centers = (const float*)d_in[1];
    const float* sigmas  = (const float*)d_in[2];
    const float* coeffs  = (const float*)d_in[3];
    float* out = (float*)d_out;
    float* nw  = (float*)d_ws;   // 512 floats

    anfis_prep<<<2, 256, 0, stream>>>(sigmas, nw);
    anfis_main<<<NS / 256, 256, 0, stream>>>(X, centers, nw, coeffs, out);
}

// Round 2
// 31.898 us; speedup vs baseline: 1.2692x; 1.2692x over previous
//
#include <hip/hip_runtime.h>

#define NS 131072
#define D 16
#define R 32
#define O 10
#define EPSF 1e-8f

typedef float v2 __attribute__((ext_vector_type(2)));

// Prologue: nw[r*D+d] = -1/(2*sigma^2). 512 elements into d_ws.
__global__ void anfis_prep(const float* __restrict__ sigmas, float* __restrict__ nw) {
    int i = blockIdx.x * blockDim.x + threadIdx.x;
    if (i < R * D) {
        float s = sigmas[i];
        nw[i] = -0.5f / (s * s);
    }
}

// Block = 256 threads = 4 waves. Wave w handles the block's 64 samples for
// rules [w*8, w*8+8). w is readfirstlane'd so rule-parameter addresses stay
// wave-uniform -> s_load (scalar cache), not per-lane vector loads.
// Partials (10 acc + ssum) reduce through LDS; wave 0 finishes softmax+store.
__global__ __launch_bounds__(256) void anfis_main(
    const float* __restrict__ X,
    const float* __restrict__ centers,
    const float* __restrict__ nw,
    const float* __restrict__ coeffs,
    float* __restrict__ out)
{
    const int tid  = threadIdx.x;
    const int lane = tid & 63;
    const int w    = __builtin_amdgcn_readfirstlane(tid >> 6);   // wave id 0..3 (SGPR)
    const int n    = blockIdx.x * 64 + lane;                     // sample index

    __shared__ float lds[256][13];   // 11 used; stride 13 -> conflict-free

    // Load this sample's 16 features.
    v2 x2[8];
    {
        const float4* xp = reinterpret_cast<const float4*>(X + (size_t)n * D);
        #pragma unroll
        for (int i = 0; i < 4; ++i) {
            float4 v = xp[i];
            x2[2*i]   = v2{v.x, v.y};
            x2[2*i+1] = v2{v.z, v.w};
        }
    }

    v2 acc[5];
    #pragma unroll
    for (int p = 0; p < 5; ++p) acc[p] = v2{0.f, 0.f};
    float ssum = 0.f;

    const int r0 = w * 8;
    #pragma unroll
    for (int j = 0; j < 8; ++j) {
        const int r = r0 + j;
        // Membership exponent: sum_d (x-c)^2 * (-1/(2 sigma^2)), packed over d.
        const v2* c2 = reinterpret_cast<const v2*>(centers + r * D);
        const v2* w2 = reinterpret_cast<const v2*>(nw + r * D);
        v2 e2 = v2{0.f, 0.f};
        #pragma unroll
        for (int i = 0; i < 8; ++i) {
            v2 df = x2[i] - c2[i];
            e2 = __builtin_elementwise_fma(df * df, w2[i], e2);
        }
        float s = __expf(e2.x + e2.y);
        ssum += s;

        // Consequent: wi_o = bias_o + sum_d x_d * C[r,d,o], packed over o-pairs.
        const v2* co = reinterpret_cast<const v2*>(coeffs + (size_t)r * ((D + 1) * O));
        v2 wi[5];
        #pragma unroll
        for (int p = 0; p < 5; ++p) wi[p] = co[D * 5 + p];   // bias row (i = D)
        #pragma unroll
        for (int d = 0; d < D; ++d) {
            float xd = (d & 1) ? x2[d >> 1].y : x2[d >> 1].x;
            v2 xd2 = v2{xd, xd};
            #pragma unroll
            for (int p = 0; p < 5; ++p)
                wi[p] = __builtin_elementwise_fma(xd2, co[d * 5 + p], wi[p]);
        }
        v2 s2 = v2{s, s};
        #pragma unroll
        for (int p = 0; p < 5; ++p)
            acc[p] = __builtin_elementwise_fma(s2, wi[p], acc[p]);
    }

    // Stash partials: lds[w*64+lane] == lds[tid].
    float* my = lds[tid];
    #pragma unroll
    for (int p = 0; p < 5; ++p) { my[2*p] = acc[p].x; my[2*p+1] = acc[p].y; }
    my[10] = ssum;
    __syncthreads();

    // Tree-fold the 4 wave partials.
    if (tid < 128) {
        #pragma unroll
        for (int k = 0; k < 11; ++k) lds[tid][k] += lds[tid + 128][k];
    }
    __syncthreads();
    if (tid < 64) {
        float a[11];
        #pragma unroll
        for (int k = 0; k < 11; ++k) a[k] = lds[tid][k] + lds[tid + 64][k];

        // Normalize (fold 1/(ssum+eps) into the softmax exponent) + softmax.
        const float inv = __builtin_amdgcn_rcpf(a[10] + EPSF);
        float m = a[0];
        #pragma unroll
        for (int o = 1; o < O; ++o) m = fmaxf(m, a[o]);
        float e_[O]; float se = 0.f;
        #pragma unroll
        for (int o = 0; o < O; ++o) { e_[o] = __expf((a[o] - m) * inv); se += e_[o]; }
        const float rs = __builtin_amdgcn_rcpf(se);

        v2* op = reinterpret_cast<v2*>(out + (size_t)n * O);   // n == blockIdx*64 + tid here
        #pragma unroll
        for (int p = 0; p < 5; ++p) op[p] = v2{e_[2*p] * rs, e_[2*p+1] * rs};
    }
}

extern "C" void kernel_launch(void* const* d_in, const int* in_sizes, int n_in,
                              void* d_out, int out_size, void* d_ws, size_t ws_size,
                              hipStream_t stream) {
    const float* X       = (const float*)d_in[0];
    const float* centers = (const float*)d_in[1];
    const float* sigmas  = (const float*)d_in[2];
    const float* coeffs  = (const float*)d_in[3];
    float* out = (float*)d_out;
    float* nw  = (float*)d_ws;   // 512 floats of scratch

    anfis_prep<<<2, 256, 0, stream>>>(sigmas, nw);
    anfis_main<<<NS / 64, 256, 0, stream>>>(X, centers, nw, coeffs, out);
}

// Round 3
// 28.880 us; speedup vs baseline: 1.4018x; 1.1045x over previous
//
#include <hip/hip_runtime.h>

#define NS 131072
#define D 16
#define R 32
#define O 10
#define EPSF 1e-8f

typedef float v2 __attribute__((ext_vector_type(2)));

// Prologue: nw[r*D+d] = -1/(2*sigma^2). 512 elements into d_ws.
__global__ void anfis_prep(const float* __restrict__ sigmas, float* __restrict__ nw) {
    int i = blockIdx.x * blockDim.x + threadIdx.x;
    if (i < R * D) {
        float s = sigmas[i];
        nw[i] = -0.5f / (s * s);
    }
}

// Block = 256 threads = 4 waves. Wave w handles the block's 64 samples for
// rules [w*8, w*8+8). w is readfirstlane'd so rule-parameter addresses stay
// wave-uniform -> s_load (scalar cache), not per-lane vector loads.
// __launch_bounds__(256, 8): pin 8 blocks/CU (8 waves/SIMD) — forces
// VGPR<=64 / SGPR<=~100 so occupancy can't silently drop to 4 waves/SIMD.
__global__ __launch_bounds__(256, 8) void anfis_main(
    const float* __restrict__ X,
    const float* __restrict__ centers,
    const float* __restrict__ nw,
    const float* __restrict__ coeffs,
    float* __restrict__ out)
{
    const int tid  = threadIdx.x;
    const int lane = tid & 63;
    const int w    = __builtin_amdgcn_readfirstlane(tid >> 6);   // wave id 0..3 (SGPR)
    const int n    = blockIdx.x * 64 + lane;                     // sample index

    __shared__ float lds[256][13];   // 11 used; stride 13 -> conflict-free

    // Load this sample's 16 features.
    v2 x2[8];
    {
        const float4* xp = reinterpret_cast<const float4*>(X + (size_t)n * D);
        #pragma unroll
        for (int i = 0; i < 4; ++i) {
            float4 v = xp[i];
            x2[2*i]   = v2{v.x, v.y};
            x2[2*i+1] = v2{v.z, v.w};
        }
    }

    v2 acc[5];
    #pragma unroll
    for (int p = 0; p < 5; ++p) acc[p] = v2{0.f, 0.f};
    float ssum = 0.f;

    const int r0 = w * 8;
    #pragma unroll
    for (int j = 0; j < 8; ++j) {
        const int r = r0 + j;
        // Membership exponent: sum_d (x-c)^2 * (-1/(2 sigma^2)), packed over d.
        const v2* c2 = reinterpret_cast<const v2*>(centers + r * D);
        const v2* w2 = reinterpret_cast<const v2*>(nw + r * D);
        v2 e2 = v2{0.f, 0.f};
        #pragma unroll
        for (int i = 0; i < 8; ++i) {
            v2 df = x2[i] - c2[i];
            e2 = __builtin_elementwise_fma(df * df, w2[i], e2);
        }
        float s = __expf(e2.x + e2.y);
        ssum += s;

        // Consequent: wi_o = bias_o + sum_d x_d * C[r,d,o], packed over o-pairs.
        const v2* co = reinterpret_cast<const v2*>(coeffs + (size_t)r * ((D + 1) * O));
        v2 wi[5];
        #pragma unroll
        for (int p = 0; p < 5; ++p) wi[p] = co[D * 5 + p];   // bias row (i = D)
        #pragma unroll
        for (int d = 0; d < D; ++d) {
            float xd = (d & 1) ? x2[d >> 1].y : x2[d >> 1].x;
            v2 xd2 = v2{xd, xd};
            #pragma unroll
            for (int p = 0; p < 5; ++p)
                wi[p] = __builtin_elementwise_fma(xd2, co[d * 5 + p], wi[p]);
        }
        v2 s2 = v2{s, s};
        #pragma unroll
        for (int p = 0; p < 5; ++p)
            acc[p] = __builtin_elementwise_fma(s2, wi[p], acc[p]);
    }

    // Stash partials: lds[w*64+lane] == lds[tid].
    float* my = lds[tid];
    #pragma unroll
    for (int p = 0; p < 5; ++p) { my[2*p] = acc[p].x; my[2*p+1] = acc[p].y; }
    my[10] = ssum;
    __syncthreads();

    // Tree-fold the 4 wave partials.
    if (tid < 128) {
        #pragma unroll
        for (int k = 0; k < 11; ++k) lds[tid][k] += lds[tid + 128][k];
    }
    __syncthreads();
    if (tid < 64) {
        float a[11];
        #pragma unroll
        for (int k = 0; k < 11; ++k) a[k] = lds[tid][k] + lds[tid + 64][k];

        // Normalize (fold 1/(ssum+eps) into the softmax exponent) + softmax.
        const float inv = __builtin_amdgcn_rcpf(a[10] + EPSF);
        float m = a[0];
        #pragma unroll
        for (int o = 1; o < O; ++o) m = fmaxf(m, a[o]);
        float e_[O]; float se = 0.f;
        #pragma unroll
        for (int o = 0; o < O; ++o) { e_[o] = __expf((a[o] - m) * inv); se += e_[o]; }
        const float rs = __builtin_amdgcn_rcpf(se);

        v2* op = reinterpret_cast<v2*>(out + (size_t)n * O);   // n == blockIdx*64 + tid here
        #pragma unroll
        for (int p = 0; p < 5; ++p) op[p] = v2{e_[2*p] * rs, e_[2*p+1] * rs};
    }
}

extern "C" void kernel_launch(void* const* d_in, const int* in_sizes, int n_in,
                              void* d_out, int out_size, void* d_ws, size_t ws_size,
                              hipStream_t stream) {
    const float* X       = (const float*)d_in[0];
    const float* centers = (const float*)d_in[1];
    const float* sigmas  = (const float*)d_in[2];
    const float* coeffs  = (const float*)d_in[3];
    float* out = (float*)d_out;
    float* nw  = (float*)d_ws;   // 512 floats of scratch

    anfis_prep<<<2, 256, 0, stream>>>(sigmas, nw);
    anfis_main<<<NS / 64, 256, 0, stream>>>(X, centers, nw, coeffs, out);
}

// Round 4
// 25.119 us; speedup vs baseline: 1.6116x; 1.1497x over previous
//
#include <hip/hip_runtime.h>

#define NS 131072
#define D 16
#define R 32
#define O 10
#define KTOT 544          // R*D (affine) + R (bias block)
#define EPSF 1e-8f

typedef float v2     __attribute__((ext_vector_type(2)));
typedef float f32x4  __attribute__((ext_vector_type(4)));
typedef short bf16x8 __attribute__((ext_vector_type(8)));

// f32 -> bf16 bits, round-nearest-even
static __device__ __forceinline__ short bf(float f) {
    union { float f; unsigned u; } v; v.f = f;
    unsigned r = (v.u + 0x7fffu + ((v.u >> 16) & 1u)) >> 16;
    return (short)r;
}

// prep: nw[r*16+d] = -1/(2 sigma^2);  Ct[o][k] bf16 (o<16 rows, K=544):
//   k < 512: Ct[o][r*16+d] = coeffs[r, d, o]     (zero for o>=10)
//   k >= 512: Ct[o][512+r] = coeffs[r, D, o]     (bias)
__global__ void anfis_prep(const float* __restrict__ sigmas,
                           const float* __restrict__ coeffs,
                           float* __restrict__ nw,
                           unsigned short* __restrict__ Ct) {
    int i = blockIdx.x * blockDim.x + threadIdx.x;
    if (i < R * D) { float s = sigmas[i]; nw[i] = -0.5f / (s * s); }
    if (i < 16 * KTOT) {
        int o = i / KTOT, k = i % KTOT;
        float v = 0.f;
        if (o < O) {
            if (k < R * D) { int r = k >> 4, d = k & 15; v = coeffs[(r * (D + 1) + d) * O + o]; }
            else           { int r = k - R * D;          v = coeffs[(r * (D + 1) + D) * O + o]; }
        }
        Ct[i] = (unsigned short)bf(v);
    }
}

// Block = 256 thr (4 waves) over 64 samples. Wave w: membership for rules
// [8w,8w+8) (VALU, scalar-path params), then consequent via MFMA on
// Z[n, k] = norm[n,r]*x[n,d] staged in wave-private swizzled LDS.
__global__ __launch_bounds__(256, 4) void anfis_main(
    const float* __restrict__ X,
    const float* __restrict__ centers,
    const float* __restrict__ nw,
    const unsigned short* __restrict__ Ct,
    float* __restrict__ out)
{
    const int tid  = threadIdx.x;
    const int lane = tid & 63;
    const int w    = __builtin_amdgcn_readfirstlane(tid >> 6);
    const int n    = blockIdx.x * 64 + lane;          // this lane's sample

    __shared__ bf16x8 zbuf[4 * 256];                  // per-wave Z: 64 rows x 4 chunks (16B)
    __shared__ float  red[4][64][17];                 // per-wave C-partials, padded stride
    __shared__ float  sbuf[256];                      // ssum partials

    bf16x8* zw = zbuf + w * 256;

    // ---- load x (16 features) ----
    v2 x2[8];
    {
        const float4* xp = reinterpret_cast<const float4*>(X + (size_t)n * D);
        #pragma unroll
        for (int i = 0; i < 4; ++i) {
            float4 v = xp[i];
            x2[2*i]   = v2{v.x, v.y};
            x2[2*i+1] = v2{v.z, v.w};
        }
    }

    // ---- membership for this wave's 8 rules ----
    float s[8];
    const int r0 = w * 8;
    float psum = 0.f;
    #pragma unroll
    for (int j = 0; j < 8; ++j) {
        const int r = r0 + j;
        const v2* c2 = reinterpret_cast<const v2*>(centers + r * D);
        const v2* w2 = reinterpret_cast<const v2*>(nw + r * D);
        v2 e2 = v2{0.f, 0.f};
        #pragma unroll
        for (int i = 0; i < 8; ++i) {
            v2 df = x2[i] - c2[i];
            e2 = __builtin_elementwise_fma(df * df, w2[i], e2);
        }
        s[j] = __expf(e2.x + e2.y);
        psum += s[j];
    }

    // ---- cross-wave ssum, then lane-local normalized strengths ----
    sbuf[tid] = psum;
    __syncthreads();
    float tot = sbuf[lane] + sbuf[lane + 64] + sbuf[lane + 128] + sbuf[lane + 192];
    const float inv = __builtin_amdgcn_rcpf(tot + EPSF);
    float nrm[8];
    #pragma unroll
    for (int j = 0; j < 8; ++j) nrm[j] = s[j] * inv;

    // ---- B-fragments: one-time vector loads from Ct (L2-hot) ----
    // frag p covers k in [w*128 + p*32, +32) for p<4; p==4 covers bias k [512,544).
    // lane: col o = lane&15, k-group g = lane>>4, 8 consecutive k.
    bf16x8 bfrag[5];
    {
        const int o = lane & 15, g = lane >> 4;
        #pragma unroll
        for (int p = 0; p < 5; ++p) {
            const int k0 = (p < 4) ? (w * 128 + p * 32) : (R * D);
            bfrag[p] = *reinterpret_cast<const bf16x8*>(Ct + o * KTOT + k0 + g * 8);
        }
    }

    f32x4 acc[4];
    #pragma unroll
    for (int rt = 0; rt < 4; ++rt) acc[rt] = f32x4{0.f, 0.f, 0.f, 0.f};

    // swizzled 16B-slot index within the wave's 256-slot Z region
    #define ZPHYS(row, chunk) ((((row) * 4 + (chunk)) ^ (((row) >> 1) & 7)))

    // ---- 5 phases: p<4 => 2 rules (K=32); p==4 => bias block (K=32) ----
    #pragma unroll
    for (int p = 0; p < 5; ++p) {
        bf16x8 zz[4];
        if (p < 4) {
            // z[k = q*16 + d] = nrm[2p+q] * x[d]; chunk j holds k j*8..j*8+7
            #pragma unroll
            for (int q = 0; q < 2; ++q) {
                const float nq = nrm[2 * p + q];
                #pragma unroll
                for (int i = 0; i < 8; ++i) {         // d = 2i, 2i+1
                    v2 t = x2[i] * nq;
                    zz[q * 2 + (i >> 2)][(i & 3) * 2 + 0] = bf(t.x);
                    zz[q * 2 + (i >> 2)][(i & 3) * 2 + 1] = bf(t.y);
                }
            }
        } else {
            // bias: k-slot g*8+j <-> rule g*8+j; this wave supplies chunk w only
            #pragma unroll
            for (int j = 0; j < 4; ++j) {
                bf16x8 z = bf16x8{0,0,0,0,0,0,0,0};
                if (j == w) {
                    #pragma unroll
                    for (int e = 0; e < 8; ++e) z[e] = bf(nrm[e]);
                }
                zz[j] = z;
            }
        }
        #pragma unroll
        for (int j = 0; j < 4; ++j)
            zw[ZPHYS(lane, j)] = zz[j];
        // wave-private LDS: compiler inserts lgkmcnt wait; no __syncthreads needed
        #pragma unroll
        for (int rt = 0; rt < 4; ++rt) {
            const int row = (lane & 15) + rt * 16;
            bf16x8 af = zw[ZPHYS(row, lane >> 4)];
            acc[rt] = __builtin_amdgcn_mfma_f32_16x16x32_bf16(af, bfrag[p], acc[rt], 0, 0, 0);
        }
    }

    // ---- stash C-partials: D layout col=lane&15, row=(lane>>4)*4+reg ----
    {
        const int col = lane & 15, g = lane >> 4;
        #pragma unroll
        for (int rt = 0; rt < 4; ++rt) {
            #pragma unroll
            for (int j = 0; j < 4; ++j)
                red[w][rt * 16 + g * 4 + j][col] = acc[rt][j];
        }
    }
    __syncthreads();

    // ---- epilogue: wave 0, lane = sample; sum 4 wave-partials, softmax, store ----
    if (tid < 64) {
        float a[O];
        #pragma unroll
        for (int o = 0; o < O; ++o)
            a[o] = red[0][tid][o] + red[1][tid][o] + red[2][tid][o] + red[3][tid][o];
        float m = a[0];
        #pragma unroll
        for (int o = 1; o < O; ++o) m = fmaxf(m, a[o]);
        float e_[O]; float se = 0.f;
        #pragma unroll
        for (int o = 0; o < O; ++o) { e_[o] = __expf(a[o] - m); se += e_[o]; }
        const float rs = __builtin_amdgcn_rcpf(se);
        float2* op = reinterpret_cast<float2*>(out + (size_t)(blockIdx.x * 64 + tid) * O);
        #pragma unroll
        for (int p = 0; p < 5; ++p) op[p] = make_float2(e_[2*p] * rs, e_[2*p+1] * rs);
    }
}

extern "C" void kernel_launch(void* const* d_in, const int* in_sizes, int n_in,
                              void* d_out, int out_size, void* d_ws, size_t ws_size,
                              hipStream_t stream) {
    const float* X       = (const float*)d_in[0];
    const float* centers = (const float*)d_in[1];
    const float* sigmas  = (const float*)d_in[2];
    const float* coeffs  = (const float*)d_in[3];
    float* out = (float*)d_out;

    float* nw = (float*)d_ws;                                  // 512 f32
    unsigned short* Ct = (unsigned short*)((char*)d_ws + 4096); // 16*544 bf16

    anfis_prep<<<(16 * KTOT + 255) / 256, 256, 0, stream>>>(sigmas, coeffs, nw, Ct);
    anfis_main<<<NS / 64, 256, 0, stream>>>(X, centers, nw, Ct, out);
}

// Round 5
// 23.711 us; speedup vs baseline: 1.7074x; 1.0594x over previous
//
#include <hip/hip_runtime.h>

#define NS 131072
#define D 16
#define R 32
#define O 10
#define KTOT 544          // R*D (affine) + R (bias block)
#define EPSF 1e-8f

typedef float v2     __attribute__((ext_vector_type(2)));
typedef float f32x4  __attribute__((ext_vector_type(4)));
typedef short bf16x8 __attribute__((ext_vector_type(8)));

// f32 -> bf16 bits, round-nearest-even (host-side path / prep only)
static __device__ __forceinline__ short bf(float f) {
    union { float f; unsigned u; } v; v.f = f;
    unsigned r = (v.u + 0x7fffu + ((v.u >> 16) & 1u)) >> 16;
    return (short)r;
}

// packed f32x2 -> bf16x2 in one HW instr (no builtin on gfx950; T12 pattern)
static __device__ __forceinline__ unsigned cvtpk(float lo, float hi) {
    unsigned r;
    asm("v_cvt_pk_bf16_f32 %0, %1, %2" : "=v"(r) : "v"(lo), "v"(hi));
    return r;
}

// prep:
//  nw [r*16+d] = w   = -1/(2 s^2)
//  nm1[r*16+d] = -2wc = c/s^2
//  nc0[r]      = sum_d w c^2
//  Ct[o][k] bf16, o<16 rows, K=544: k<512 -> coeffs[r,d,o] (r=k>>4,d=k&15); k>=512 -> bias coeffs[r,D,o]
__global__ void anfis_prep(const float* __restrict__ sigmas,
                           const float* __restrict__ centers,
                           const float* __restrict__ coeffs,
                           float* __restrict__ nw,
                           float* __restrict__ nm1,
                           float* __restrict__ nc0,
                           unsigned short* __restrict__ Ct) {
    int i = blockIdx.x * blockDim.x + threadIdx.x;
    if (i < R * D) {
        float s = sigmas[i], c = centers[i];
        float w = -0.5f / (s * s);
        nw[i]  = w;
        nm1[i] = -2.0f * w * c;
    }
    if (i < R) {
        float acc = 0.f;
        for (int d = 0; d < D; ++d) {
            float s = sigmas[i * D + d], c = centers[i * D + d];
            acc += (-0.5f / (s * s)) * c * c;
        }
        nc0[i] = acc;
    }
    if (i < 16 * KTOT) {
        int o = i / KTOT, k = i % KTOT;
        float v = 0.f;
        if (o < O) {
            if (k < R * D) { int r = k >> 4, d = k & 15; v = coeffs[(r * (D + 1) + d) * O + o]; }
            else           { int r = k - R * D;          v = coeffs[(r * (D + 1) + D) * O + o]; }
        }
        Ct[i] = (unsigned short)bf(v);
    }
}

// Block = 256 thr (4 waves) over 64 samples. Wave w: membership for rules
// [8w,8w+8), then consequent via MFMA on Z[n,k]=norm[n,r]*x[n,d] staged in
// wave-private swizzled LDS. red-partials overlay the Z buffer (wave-private
// for both uses -> no extra barrier). launch_bounds(256,8): 8 blocks/CU.
__global__ __launch_bounds__(256, 8) void anfis_main(
    const float* __restrict__ X,
    const float* __restrict__ nw,
    const float* __restrict__ nm1,
    const float* __restrict__ nc0,
    const unsigned short* __restrict__ Ct,
    float* __restrict__ out)
{
    const int tid  = threadIdx.x;
    const int lane = tid & 63;
    const int w    = __builtin_amdgcn_readfirstlane(tid >> 6);
    const int n    = blockIdx.x * 64 + lane;

    // per-wave 4352B region: phases use it as Z (64 rows x 4 x 16B = 4096B),
    // then as C-partials (64 rows x 17 f32 = 4352B). sbuf separate.
    __shared__ char  lbuf[4 * 4352];
    __shared__ float sbuf[256];
    bf16x8* zw = reinterpret_cast<bf16x8*>(lbuf + w * 4352);
    float*  rw = reinterpret_cast<float*> (lbuf + w * 4352);

    // ---- load x ----
    v2 x2[8];
    {
        const float4* xp = reinterpret_cast<const float4*>(X + (size_t)n * D);
        #pragma unroll
        for (int i = 0; i < 4; ++i) {
            float4 v = xp[i];
            x2[2*i]   = v2{v.x, v.y};
            x2[2*i+1] = v2{v.z, v.w};
        }
    }

    // ---- B-fragment prefetch for phase 0 (L2-hot) ----
    const int o = lane & 15, g = lane >> 4;
    const unsigned short* cbase = Ct + o * KTOT + g * 8;
    bf16x8 bnext = *reinterpret_cast<const bf16x8*>(cbase + w * 128);

    // ---- membership: e = sum_d (w x^2 + m1 x) + c0 ----
    float s[8];
    float psum = 0.f;
    {
        v2 xsq[8];
        #pragma unroll
        for (int i = 0; i < 8; ++i) xsq[i] = x2[i] * x2[i];
        const int r0 = w * 8;
        #pragma unroll
        for (int j = 0; j < 8; ++j) {
            const int r = r0 + j;
            const v2* W2 = reinterpret_cast<const v2*>(nw  + r * D);
            const v2* M2 = reinterpret_cast<const v2*>(nm1 + r * D);
            v2 e2 = v2{0.f, 0.f};
            #pragma unroll
            for (int i = 0; i < 8; ++i) {
                e2 = __builtin_elementwise_fma(xsq[i], W2[i], e2);
                e2 = __builtin_elementwise_fma(x2[i],  M2[i], e2);
            }
            s[j] = __expf(e2.x + e2.y + nc0[r]);
            psum += s[j];
        }
    }

    // ---- cross-wave ssum; lane-local normalized strengths ----
    sbuf[tid] = psum;
    __syncthreads();
    float tot = sbuf[lane] + sbuf[lane + 64] + sbuf[lane + 128] + sbuf[lane + 192];
    const float inv = __builtin_amdgcn_rcpf(tot + EPSF);
    float nrm[8];
    #pragma unroll
    for (int j = 0; j < 8; ++j) nrm[j] = s[j] * inv;

    f32x4 acc[4];
    #pragma unroll
    for (int rt = 0; rt < 4; ++rt) acc[rt] = f32x4{0.f, 0.f, 0.f, 0.f};

    // swizzled 16B-slot index within the wave's 256-slot Z region
    #define ZPHYS(row, chunk) ((((row) * 4 + (chunk)) ^ (((row) >> 1) & 7)))

    // ---- 5 phases: p<4 => 2 rules (K=32); p==4 => bias block ----
    #pragma unroll
    for (int p = 0; p < 5; ++p) {
        bf16x8 bcur = bnext;
        if (p < 4) {
            const int k0n = (p + 1 < 4) ? (w * 128 + (p + 1) * 32) : (R * D);
            bnext = *reinterpret_cast<const bf16x8*>(cbase + k0n);
        }
        if (p < 4) {
            // z[k=q*16+d] = nrm[2p+q]*x[d]; chunk j: rule q=j>>1, d-range (j&1)*8..+8
            #pragma unroll
            for (int j = 0; j < 4; ++j) {
                const float nq = nrm[2 * p + (j >> 1)];
                union { unsigned u[4]; bf16x8 v; } ch;
                #pragma unroll
                for (int m = 0; m < 4; ++m) {
                    v2 t = x2[(j & 1) * 4 + m] * nq;
                    ch.u[m] = cvtpk(t.x, t.y);
                }
                zw[ZPHYS(lane, j)] = ch.v;
            }
        } else {
            // bias: k-slot g*8+e <-> rule g*8+e; this wave supplies chunk w only
            #pragma unroll
            for (int j = 0; j < 4; ++j) {
                union { unsigned u[4]; bf16x8 v; } ch;
                #pragma unroll
                for (int m = 0; m < 4; ++m)
                    ch.u[m] = (j == w) ? cvtpk(nrm[2 * m], nrm[2 * m + 1]) : 0u;
                zw[ZPHYS(lane, j)] = ch.v;
            }
        }
        #pragma unroll
        for (int rt = 0; rt < 4; ++rt) {
            bf16x8 af = zw[ZPHYS((lane & 15) + rt * 16, g)];
            acc[rt] = __builtin_amdgcn_mfma_f32_16x16x32_bf16(af, bcur, acc[rt], 0, 0, 0);
        }
    }

    // ---- stash C-partials over the Z region (wave-private, ordered by data deps) ----
    #pragma unroll
    for (int rt = 0; rt < 4; ++rt) {
        #pragma unroll
        for (int j = 0; j < 4; ++j)
            rw[(rt * 16 + g * 4 + j) * 17 + o] = acc[rt][j];
    }
    __syncthreads();

    // ---- epilogue: wave 0, lane = sample ----
    if (tid < 64) {
        float a[O];
        #pragma unroll
        for (int oo = 0; oo < O; ++oo) {
            a[oo] = reinterpret_cast<const float*>(lbuf +    0)[tid * 17 + oo]
                  + reinterpret_cast<const float*>(lbuf + 4352)[tid * 17 + oo]
                  + reinterpret_cast<const float*>(lbuf + 8704)[tid * 17 + oo]
                  + reinterpret_cast<const float*>(lbuf +13056)[tid * 17 + oo];
        }
        float m = a[0];
        #pragma unroll
        for (int oo = 1; oo < O; ++oo) m = fmaxf(m, a[oo]);
        float e_[O]; float se = 0.f;
        #pragma unroll
        for (int oo = 0; oo < O; ++oo) { e_[oo] = __expf(a[oo] - m); se += e_[oo]; }
        const float rs = __builtin_amdgcn_rcpf(se);
        float2* op = reinterpret_cast<float2*>(out + (size_t)(blockIdx.x * 64 + tid) * O);
        #pragma unroll
        for (int pp = 0; pp < 5; ++pp) op[pp] = make_float2(e_[2*pp] * rs, e_[2*pp+1] * rs);
    }
}

extern "C" void kernel_launch(void* const* d_in, const int* in_sizes, int n_in,
                              void* d_out, int out_size, void* d_ws, size_t ws_size,
                              hipStream_t stream) {
    const float* X       = (const float*)d_in[0];
    const float* centers = (const float*)d_in[1];
    const float* sigmas  = (const float*)d_in[2];
    const float* coeffs  = (const float*)d_in[3];
    float* out = (float*)d_out;

    float* nw  = (float*)d_ws;                                   // 512 f32 @ 0
    float* nm1 = (float*)((char*)d_ws + 2048);                   // 512 f32
    float* nc0 = (float*)((char*)d_ws + 4096);                   // 32 f32
    unsigned short* Ct = (unsigned short*)((char*)d_ws + 4224);  // 16*544 bf16

    anfis_prep<<<(16 * KTOT + 255) / 256, 256, 0, stream>>>(sigmas, centers, coeffs,
                                                            nw, nm1, nc0, Ct);
    anfis_main<<<NS / 64, 256, 0, stream>>>(X, nw, nm1, nc0, Ct, out);
}